// Round 8
// baseline (210.722 us; speedup 1.0000x reference)
//
#include <hip/hip_runtime.h>
#include <math.h>

#define D 128
#define NPARAMS 16
#define H 256
#define XCOLS (D + NPARAMS)   // 144
#define BATCH 4096
#define NTOT (BATCH * D)      // 524288
#define WVS 16                // waves per MLP block (= samples per block)

#define INV_2PI_F 0.15915494309189535f
#define OUT_SCALE 2.5132741228718345f   // 2*pi / 2.5

// ---------------- weight pre-pack: pw[k4][j][kk] = W[j][4*k4+kk] -------------
// Lane j loads float4 at (k4*H + j)*16 -> consecutive lanes, consecutive 16B.

__global__ __launch_bounds__(256) void pack_kernel(
    const float* __restrict__ w_in, const float* __restrict__ w0,
    const float* __restrict__ w1,   const float* __restrict__ w_out,
    float* __restrict__ pw_in, float* __restrict__ pw0,
    float* __restrict__ pw1,   float* __restrict__ pwo)
{
    int t = blockIdx.x * 256 + threadIdx.x;   // 0..65535
    {
        int j = t >> 8, k = t & 255;
        int dst = (k >> 2) * (H * 4) + j * 4 + (k & 3);
        pw0[dst] = w0[t];
        pw1[dst] = w1[t];
        pwo[dst] = w_out[t];
    }
    if (t < H * NPARAMS) {
        int j = t >> 4, k = t & 15;
        pw_in[(k >> 2) * (H * 4) + j * 4 + (k & 3)] = w_in[t];
    }
}

// ---------------- MLP: one wave per sample, 4 outputs per thread -------------
// Per k4 step: 1 broadcast ds_read_b128 (activations) + 4 coalesced weight
// float4 loads + 16 FMAs. 16 waves/block barrier-paced on the same weight
// stream -> L1 reuse. acc[m] holds output j = lane + 64*m.

template<int K4N>
__device__ __forceinline__ void layer_w(
    const float4* __restrict__ pw, const float* __restrict__ bias,
    const float* __restrict__ src, float acc[4], int lane)
{
    acc[0] = bias[lane];
    acc[1] = bias[lane + 64];
    acc[2] = bias[lane + 128];
    acc[3] = bias[lane + 192];

    const float4* wp = pw + lane;
    const float4* s4 = reinterpret_cast<const float4*>(src);

    float4 wr[2][4];
    float4 ar[2];
    #pragma unroll
    for (int m = 0; m < 4; ++m) wr[0][m] = wp[64 * m];
    ar[0] = s4[0];
    #pragma unroll
    for (int m = 0; m < 4; ++m) wr[1][m] = wp[H + 64 * m];
    ar[1] = s4[1];

    #pragma unroll 4
    for (int k4 = 0; k4 < K4N; ++k4) {
        float4 av = ar[k4 & 1];
        float4 w0 = wr[k4 & 1][0], w1 = wr[k4 & 1][1];
        float4 w2 = wr[k4 & 1][2], w3 = wr[k4 & 1][3];
        if (k4 + 2 < K4N) {
            #pragma unroll
            for (int m = 0; m < 4; ++m) wr[k4 & 1][m] = wp[(k4 + 2) * H + 64 * m];
            ar[k4 & 1] = s4[k4 + 2];
        }
        acc[0] = fmaf(w0.x, av.x, acc[0]); acc[0] = fmaf(w0.y, av.y, acc[0]);
        acc[0] = fmaf(w0.z, av.z, acc[0]); acc[0] = fmaf(w0.w, av.w, acc[0]);
        acc[1] = fmaf(w1.x, av.x, acc[1]); acc[1] = fmaf(w1.y, av.y, acc[1]);
        acc[1] = fmaf(w1.z, av.z, acc[1]); acc[1] = fmaf(w1.w, av.w, acc[1]);
        acc[2] = fmaf(w2.x, av.x, acc[2]); acc[2] = fmaf(w2.y, av.y, acc[2]);
        acc[2] = fmaf(w2.z, av.z, acc[2]); acc[2] = fmaf(w2.w, av.w, acc[2]);
        acc[3] = fmaf(w3.x, av.x, acc[3]); acc[3] = fmaf(w3.y, av.y, acc[3]);
        acc[3] = fmaf(w3.z, av.z, acc[3]); acc[3] = fmaf(w3.w, av.w, acc[3]);
    }
}

__global__ __launch_bounds__(1024, 4) void mlp_kernel(
    const float* __restrict__ x,
    const float4* __restrict__ pw_in, const float* __restrict__ b_in,
    const float4* __restrict__ pw0,   const float* __restrict__ b0,
    const float4* __restrict__ pw1,   const float* __restrict__ b1,
    const float4* __restrict__ pwo,   const float* __restrict__ b_out,
    float* __restrict__ w2buf, float* __restrict__ cbuf)
{
    __shared__ float act[WVS][2][H];   // 32 KB: per-wave ping/pong activations
    const int lane = threadIdx.x & 63;
    const int wv   = threadIdx.x >> 6;
    const int b    = blockIdx.x * WVS + wv;

    float* A = &act[wv][0][0];
    float* B = &act[wv][1][0];

    if (lane < NPARAMS) A[lane] = x[b * XCOLS + D + lane];
    __syncthreads();

    float acc[4];

    layer_w<NPARAMS / 4>(pw_in, b_in, A, acc, lane);
    #pragma unroll
    for (int m = 0; m < 4; ++m) B[lane + 64 * m] = fmaxf(acc[m], 0.f);
    __syncthreads();

    layer_w<H / 4>(pw0, b0, B, acc, lane);
    #pragma unroll
    for (int m = 0; m < 4; ++m) A[lane + 64 * m] = fmaxf(acc[m], 0.f);
    __syncthreads();

    layer_w<H / 4>(pw1, b1, A, acc, lane);
    #pragma unroll
    for (int m = 0; m < 4; ++m) B[lane + 64 * m] = fmaxf(acc[m], 0.f);
    __syncthreads();

    layer_w<H / 4>(pwo, b_out, B, acc, lane);
    // j = lane+64m: m=0,1 -> omega0 (j<128); m=2,3 -> coupling (j-128)
    float om0 = fmaf(acc[0], 1.5f, 0.5f);
    float om1 = fmaf(acc[1], 1.5f, 0.5f);
    w2buf[b * D + lane]      = om0 * om0 * INV_2PI_F;
    w2buf[b * D + 64 + lane] = om1 * om1 * INV_2PI_F;
    cbuf[b * D + lane]       = acc[2];
    cbuf[b * D + 64 + lane]  = acc[3];
}

// ---------------- ODE: revolution-domain RK4, 2 samples per wave -------------

__device__ __forceinline__ float rot_from_lower(float v) {  // lane n <- lane (n-1)&63
    return __int_as_float(__builtin_amdgcn_mov_dpp(__float_as_int(v), 0x13C, 0xF, 0xF, false)); // wave_ror:1
}
__device__ __forceinline__ float rot_from_upper(float v) {  // lane n <- lane (n+1)&63
    return __int_as_float(__builtin_amdgcn_mov_dpp(__float_as_int(v), 0x134, 0xF, 0xF, false)); // wave_rol:1
}

__global__ __launch_bounds__(256) void ode_kernel(
    const float* __restrict__ x,
    const float* __restrict__ w2buf,
    const float* __restrict__ cbuf,
    float* __restrict__ out,
    int nstep, float dt)
{
    const int lane = threadIdx.x & 63;
    const int wid  = threadIdx.x >> 6;
    const int bA   = blockIdx.x * 8 + wid * 2;   // two consecutive samples

    float th0[2], th1[2], v0[2], v1[2];
    float nw0[2], nw1[2], c0[2], c1[2], cl[2];

    #pragma unroll
    for (int s = 0; s < 2; ++s) {
        int b  = bA + s;
        int i0 = b * D + 2 * lane;
        float2 xi  = *reinterpret_cast<const float2*>(&x[b * XCOLS + 2 * lane]);
        th0[s] = xi.x - 0.5f;            // phi0 = x - 1/2 (revolutions)
        th1[s] = xi.y - 0.5f;
        v0[s] = 0.f; v1[s] = 0.f;
        float2 w2p = *reinterpret_cast<const float2*>(&w2buf[i0]);
        float2 cp  = *reinterpret_cast<const float2*>(&cbuf[i0]);
        nw0[s] = -w2p.x; nw1[s] = -w2p.y;
        c0[s] = cp.x;    c1[s] = cp.y;
        cl[s] = cbuf[(i0 + NTOT - 1) % NTOT];   // flat-roll left coupling of osc 2l
    }

    auto deriv = [&](const float t0[2], const float t1[2], float a0[2], float a1[2]) {
        #pragma unroll
        for (int s = 0; s < 2; ++s) {
            float L0 = rot_from_lower(t1[s]);   // phi of osc 2l-1 (wraps 0 -> 127)
            float R1 = rot_from_upper(t0[s]);   // phi of osc 2l+2 (wraps 63 -> 0)
            float s0 = __builtin_amdgcn_sinf(t0[s]);   // sin(2pi*phi), raw v_sin_f32
            float s1 = __builtin_amdgcn_sinf(t1[s]);
            float dd  = t1[s] - t0[s];
            float cpl = c0[s] * dd;
            a0[s] = fmaf(s0, nw0[s], fmaf(cl[s], L0 - t0[s],  cpl));
            a1[s] = fmaf(s1, nw1[s], fmaf(c1[s], R1 - t1[s], -cpl));
        }
    };

    const float hdt   = 0.5f * dt;
    const float sixth = dt * (1.0f / 6.0f);

    for (int it = 0; it < nstep; ++it) {
        float a1_0[2], a1_1[2];
        deriv(th0, th1, a1_0, a1_1);

        float t2_0[2], t2_1[2], k2_0[2], k2_1[2];
        #pragma unroll
        for (int s = 0; s < 2; ++s) {
            t2_0[s] = fmaf(hdt, v0[s], th0[s]);   t2_1[s] = fmaf(hdt, v1[s], th1[s]);
            k2_0[s] = fmaf(hdt, a1_0[s], v0[s]);  k2_1[s] = fmaf(hdt, a1_1[s], v1[s]);
        }
        float a2_0[2], a2_1[2];
        deriv(t2_0, t2_1, a2_0, a2_1);

        float t3_0[2], t3_1[2], k3_0[2], k3_1[2];
        #pragma unroll
        for (int s = 0; s < 2; ++s) {
            t3_0[s] = fmaf(hdt, k2_0[s], th0[s]); t3_1[s] = fmaf(hdt, k2_1[s], th1[s]);
            k3_0[s] = fmaf(hdt, a2_0[s], v0[s]);  k3_1[s] = fmaf(hdt, a2_1[s], v1[s]);
        }
        float a3_0[2], a3_1[2];
        deriv(t3_0, t3_1, a3_0, a3_1);

        float t4_0[2], t4_1[2], k4_0[2], k4_1[2];
        #pragma unroll
        for (int s = 0; s < 2; ++s) {
            t4_0[s] = fmaf(dt, k3_0[s], th0[s]);  t4_1[s] = fmaf(dt, k3_1[s], th1[s]);
            k4_0[s] = fmaf(dt, a3_0[s], v0[s]);   k4_1[s] = fmaf(dt, a3_1[s], v1[s]);
        }
        float a4_0[2], a4_1[2];
        deriv(t4_0, t4_1, a4_0, a4_1);

        #pragma unroll
        for (int s = 0; s < 2; ++s) {
            th0[s] += sixth * (v0[s] + 2.f * (k2_0[s] + k3_0[s]) + k4_0[s]);
            th1[s] += sixth * (v1[s] + 2.f * (k2_1[s] + k3_1[s]) + k4_1[s]);
            v0[s]  += sixth * (a1_0[s] + 2.f * (a2_0[s] + a3_0[s]) + a4_0[s]);
            v1[s]  += sixth * (a1_1[s] + 2.f * (a2_1[s] + a3_1[s]) + a4_1[s]);
        }
    }

    #pragma unroll
    for (int s = 0; s < 2; ++s) {
        int i0 = (bA + s) * D + 2 * lane;
        float2 o = make_float2(th0[s] * OUT_SCALE, th1[s] * OUT_SCALE);
        *reinterpret_cast<float2*>(&out[i0]) = o;
    }
}

extern "C" void kernel_launch(void* const* d_in, const int* in_sizes, int n_in,
                              void* d_out, int out_size, void* d_ws, size_t ws_size,
                              hipStream_t stream) {
    const float* x     = (const float*)d_in[0];
    const float* w_in  = (const float*)d_in[1];
    const float* b_in  = (const float*)d_in[2];
    const float* w0    = (const float*)d_in[3];
    const float* b0    = (const float*)d_in[4];
    const float* w1    = (const float*)d_in[5];
    const float* b1    = (const float*)d_in[6];
    const float* w_out = (const float*)d_in[7];
    const float* b_out = (const float*)d_in[8];

    float* w2buf = (float*)d_ws;                  // omega0^2/(2pi), NTOT floats
    float* cbuf  = w2buf + NTOT;                  // coupling, NTOT floats
    float* pw_in = cbuf + NTOT;                   // packed w_in, 4096
    float* pw0   = pw_in + H * NPARAMS;           // packed w0, 65536
    float* pw1   = pw0 + H * H;                   // packed w1, 65536
    float* pwo   = pw1 + H * H;                   // packed w_out, 65536
    float* out   = (float*)d_out;

    pack_kernel<<<H * H / 256, 256, 0, stream>>>(w_in, w0, w1, w_out,
                                                 pw_in, pw0, pw1, pwo);

    mlp_kernel<<<BATCH / WVS, 1024, 0, stream>>>(
        x, (const float4*)pw_in, b_in, (const float4*)pw0, b0,
        (const float4*)pw1, b1, (const float4*)pwo, b_out, w2buf, cbuf);

    const int nstep = 40;
    const float dtf = (float)((59.0 / 30.0) / nstep);
    ode_kernel<<<BATCH / 8, 256, 0, stream>>>(x, w2buf, cbuf, out, nstep, dtf);
}

// Round 9
// 74.604 us; speedup vs baseline: 2.8246x; 2.8246x over previous
//
#include <hip/hip_runtime.h>
#include <math.h>

#define D 128
#define NPARAMS 16
#define H 256
#define XCOLS (D + NPARAMS)   // 144
#define BATCH 4096
#define NTOT (BATCH * D)      // 524288
#define NSS 4                 // samples per wave

#define INV_2PI_F 0.15915494309189535f
#define OUT_SCALE 2.5132741228718345f   // 2*pi / 2.5

// ---------------- weight pre-pack: pw[k4][j][kk] = W[j][4*k4+kk] -------------
// float4 index = k4*H + j. Lane j loads consecutive 16B -> coalesced.

__global__ __launch_bounds__(256) void pack_kernel(
    const float* __restrict__ w_in, const float* __restrict__ w0,
    const float* __restrict__ w1,   const float* __restrict__ w_out,
    float* __restrict__ pw_in, float* __restrict__ pw0,
    float* __restrict__ pw1,   float* __restrict__ pwo)
{
    int t = blockIdx.x * 256 + threadIdx.x;   // 0..65535
    {
        int j = t >> 8, k = t & 255;
        int dst = (k >> 2) * (H * 4) + j * 4 + (k & 3);
        pw0[dst] = w0[t];
        pw1[dst] = w1[t];
        pwo[dst] = w_out[t];
    }
    if (t < H * NPARAMS) {
        int j = t >> 4, k = t & 15;
        pw_in[(k >> 2) * (H * 4) + j * 4 + (k & 3)] = w_in[t];
    }
}

// ---------------- MLP: register-resident, LDS-free ---------------------------
// Wave-autonomous: each wave owns NSS=4 samples and all 256 outputs
// (thread -> outputs lane+64m, m=0..3). Activations distributed in registers
// (act[m][s] = in[64m+lane] of sample s); broadcast via v_readlane (VALU pipe,
// parallel across SIMDs) -> zero LDS traffic, zero barriers, zero shuffles
// between layers (acc layout == act layout).

__device__ __forceinline__ float bcast(float v, int src) {
    return __int_as_float(__builtin_amdgcn_readlane(__float_as_int(v), src));
}

// one 256-wide layer: acts from act[4][NSS], weights via depth-2 ring
template<bool RELU>
__device__ __forceinline__ void layer256_rl(
    const float4* __restrict__ pw, const float* __restrict__ bias,
    const float (&act)[4][NSS], float (&out)[4][NSS], int lane)
{
    float acc[4][NSS];
    #pragma unroll
    for (int m = 0; m < 4; ++m) {
        float bb = bias[lane + 64 * m];
        #pragma unroll
        for (int s = 0; s < NSS; ++s) acc[m][s] = bb;
    }

    const float4* wp = pw + lane;
    float4 wr[2][4];
    #pragma unroll
    for (int m = 0; m < 4; ++m) wr[0][m] = wp[64 * m];
    #pragma unroll
    for (int m = 0; m < 4; ++m) wr[1][m] = wp[H + 64 * m];

    #pragma unroll
    for (int m4 = 0; m4 < 4; ++m4) {          // act register block (compile-time)
        #pragma unroll 2
        for (int k4i = 0; k4i < 16; ++k4i) {  // k4 = m4*16+k4i; k4&1 == k4i&1
            int k4 = m4 * 16 + k4i;
            float4 w0 = wr[k4i & 1][0], w1 = wr[k4i & 1][1];
            float4 w2 = wr[k4i & 1][2], w3 = wr[k4i & 1][3];
            if (m4 < 3 || k4i < 14) {         // prefetch k4+2 (uniform branch)
                #pragma unroll
                for (int m = 0; m < 4; ++m)
                    wr[k4i & 1][m] = wp[(k4 + 2) * H + 64 * m];
            }
            #pragma unroll
            for (int kk = 0; kk < 4; ++kk) {
                int src = 4 * k4i + kk;       // lane within act[m4]
                float wk0 = (&w0.x)[kk], wk1 = (&w1.x)[kk];
                float wk2 = (&w2.x)[kk], wk3 = (&w3.x)[kk];
                #pragma unroll
                for (int s = 0; s < NSS; ++s) {
                    float a = bcast(act[m4][s], src);
                    acc[0][s] = fmaf(wk0, a, acc[0][s]);
                    acc[1][s] = fmaf(wk1, a, acc[1][s]);
                    acc[2][s] = fmaf(wk2, a, acc[2][s]);
                    acc[3][s] = fmaf(wk3, a, acc[3][s]);
                }
            }
        }
    }
    #pragma unroll
    for (int m = 0; m < 4; ++m)
        #pragma unroll
        for (int s = 0; s < NSS; ++s)
            out[m][s] = RELU ? fmaxf(acc[m][s], 0.f) : acc[m][s];
}

__global__ __launch_bounds__(256) void mlp_kernel(
    const float* __restrict__ x,
    const float4* __restrict__ pw_in, const float* __restrict__ b_in,
    const float4* __restrict__ pw0,   const float* __restrict__ b0,
    const float4* __restrict__ pw1,   const float* __restrict__ b1,
    const float4* __restrict__ pwo,   const float* __restrict__ b_out,
    float* __restrict__ w2buf, float* __restrict__ cbuf)
{
    const int lane = threadIdx.x & 63;
    const int wv   = threadIdx.x >> 6;
    const int b0i  = blockIdx.x * (4 * NSS) + wv * NSS;

    // params: lane l<16 holds param[l] of each sample
    float pr[NSS];
    #pragma unroll
    for (int s = 0; s < NSS; ++s)
        pr[s] = (lane < NPARAMS) ? x[(b0i + s) * XCOLS + D + lane] : 0.f;

    float hA[4][NSS], hB[4][NSS];

    // layer in: 16 -> 256 (K4N = 4)
    {
        float acc[4][NSS];
        #pragma unroll
        for (int m = 0; m < 4; ++m) {
            float bb = b_in[lane + 64 * m];
            #pragma unroll
            for (int s = 0; s < NSS; ++s) acc[m][s] = bb;
        }
        const float4* wp = pw_in + lane;
        #pragma unroll
        for (int k4 = 0; k4 < NPARAMS / 4; ++k4) {
            float4 w0 = wp[k4 * H +   0], w1 = wp[k4 * H +  64];
            float4 w2 = wp[k4 * H + 128], w3 = wp[k4 * H + 192];
            #pragma unroll
            for (int kk = 0; kk < 4; ++kk) {
                int src = 4 * k4 + kk;
                float wk0 = (&w0.x)[kk], wk1 = (&w1.x)[kk];
                float wk2 = (&w2.x)[kk], wk3 = (&w3.x)[kk];
                #pragma unroll
                for (int s = 0; s < NSS; ++s) {
                    float a = bcast(pr[s], src);
                    acc[0][s] = fmaf(wk0, a, acc[0][s]);
                    acc[1][s] = fmaf(wk1, a, acc[1][s]);
                    acc[2][s] = fmaf(wk2, a, acc[2][s]);
                    acc[3][s] = fmaf(wk3, a, acc[3][s]);
                }
            }
        }
        #pragma unroll
        for (int m = 0; m < 4; ++m)
            #pragma unroll
            for (int s = 0; s < NSS; ++s) hA[m][s] = fmaxf(acc[m][s], 0.f);
    }

    layer256_rl<true >(pw0, b0,    hA, hB, lane);
    layer256_rl<true >(pw1, b1,    hB, hA, lane);
    layer256_rl<false>(pwo, b_out, hA, hB, lane);   // hB = coef

    // epilogue: m=0,1 -> omega0 (j = lane+64m < 128); m=2,3 -> coupling
    #pragma unroll
    for (int s = 0; s < NSS; ++s) {
        int base = (b0i + s) * D;
        float om0 = fmaf(hB[0][s], 1.5f, 0.5f);
        float om1 = fmaf(hB[1][s], 1.5f, 0.5f);
        w2buf[base + lane]      = om0 * om0 * INV_2PI_F;
        w2buf[base + 64 + lane] = om1 * om1 * INV_2PI_F;
        cbuf[base + lane]       = hB[2][s];
        cbuf[base + 64 + lane]  = hB[3][s];
    }
}

// ---------------- ODE: revolution-domain RK4, 2 samples per wave -------------

__device__ __forceinline__ float rot_from_lower(float v) {  // lane n <- lane (n-1)&63
    return __int_as_float(__builtin_amdgcn_mov_dpp(__float_as_int(v), 0x13C, 0xF, 0xF, false)); // wave_ror:1
}
__device__ __forceinline__ float rot_from_upper(float v) {  // lane n <- lane (n+1)&63
    return __int_as_float(__builtin_amdgcn_mov_dpp(__float_as_int(v), 0x134, 0xF, 0xF, false)); // wave_rol:1
}

__global__ __launch_bounds__(256) void ode_kernel(
    const float* __restrict__ x,
    const float* __restrict__ w2buf,
    const float* __restrict__ cbuf,
    float* __restrict__ out,
    int nstep, float dt)
{
    const int lane = threadIdx.x & 63;
    const int wid  = threadIdx.x >> 6;
    const int bA   = blockIdx.x * 8 + wid * 2;   // two consecutive samples

    float th0[2], th1[2], v0[2], v1[2];
    float nw0[2], nw1[2], c0[2], c1[2], cl[2];

    #pragma unroll
    for (int s = 0; s < 2; ++s) {
        int b  = bA + s;
        int i0 = b * D + 2 * lane;
        float2 xi  = *reinterpret_cast<const float2*>(&x[b * XCOLS + 2 * lane]);
        th0[s] = xi.x - 0.5f;            // phi0 = x - 1/2 (revolutions)
        th1[s] = xi.y - 0.5f;
        v0[s] = 0.f; v1[s] = 0.f;
        float2 w2p = *reinterpret_cast<const float2*>(&w2buf[i0]);
        float2 cp  = *reinterpret_cast<const float2*>(&cbuf[i0]);
        nw0[s] = -w2p.x; nw1[s] = -w2p.y;
        c0[s] = cp.x;    c1[s] = cp.y;
        cl[s] = cbuf[(i0 + NTOT - 1) % NTOT];   // flat-roll left coupling of osc 2l
    }

    auto deriv = [&](const float t0[2], const float t1[2], float a0[2], float a1[2]) {
        #pragma unroll
        for (int s = 0; s < 2; ++s) {
            float L0 = rot_from_lower(t1[s]);   // phi of osc 2l-1 (wraps 0 -> 127)
            float R1 = rot_from_upper(t0[s]);   // phi of osc 2l+2 (wraps 63 -> 0)
            float s0 = __builtin_amdgcn_sinf(t0[s]);   // sin(2pi*phi), raw v_sin_f32
            float s1 = __builtin_amdgcn_sinf(t1[s]);
            float dd  = t1[s] - t0[s];
            float cpl = c0[s] * dd;
            a0[s] = fmaf(s0, nw0[s], fmaf(cl[s], L0 - t0[s],  cpl));
            a1[s] = fmaf(s1, nw1[s], fmaf(c1[s], R1 - t1[s], -cpl));
        }
    };

    const float hdt   = 0.5f * dt;
    const float sixth = dt * (1.0f / 6.0f);

    for (int it = 0; it < nstep; ++it) {
        float a1_0[2], a1_1[2];
        deriv(th0, th1, a1_0, a1_1);

        float t2_0[2], t2_1[2], k2_0[2], k2_1[2];
        #pragma unroll
        for (int s = 0; s < 2; ++s) {
            t2_0[s] = fmaf(hdt, v0[s], th0[s]);   t2_1[s] = fmaf(hdt, v1[s], th1[s]);
            k2_0[s] = fmaf(hdt, a1_0[s], v0[s]);  k2_1[s] = fmaf(hdt, a1_1[s], v1[s]);
        }
        float a2_0[2], a2_1[2];
        deriv(t2_0, t2_1, a2_0, a2_1);

        float t3_0[2], t3_1[2], k3_0[2], k3_1[2];
        #pragma unroll
        for (int s = 0; s < 2; ++s) {
            t3_0[s] = fmaf(hdt, k2_0[s], th0[s]); t3_1[s] = fmaf(hdt, k2_1[s], th1[s]);
            k3_0[s] = fmaf(hdt, a2_0[s], v0[s]);  k3_1[s] = fmaf(hdt, a2_1[s], v1[s]);
        }
        float a3_0[2], a3_1[2];
        deriv(t3_0, t3_1, a3_0, a3_1);

        float t4_0[2], t4_1[2], k4_0[2], k4_1[2];
        #pragma unroll
        for (int s = 0; s < 2; ++s) {
            t4_0[s] = fmaf(dt, k3_0[s], th0[s]);  t4_1[s] = fmaf(dt, k3_1[s], th1[s]);
            k4_0[s] = fmaf(dt, a3_0[s], v0[s]);   k4_1[s] = fmaf(dt, a3_1[s], v1[s]);
        }
        float a4_0[2], a4_1[2];
        deriv(t4_0, t4_1, a4_0, a4_1);

        #pragma unroll
        for (int s = 0; s < 2; ++s) {
            th0[s] += sixth * (v0[s] + 2.f * (k2_0[s] + k3_0[s]) + k4_0[s]);
            th1[s] += sixth * (v1[s] + 2.f * (k2_1[s] + k3_1[s]) + k4_1[s]);
            v0[s]  += sixth * (a1_0[s] + 2.f * (a2_0[s] + a3_0[s]) + a4_0[s]);
            v1[s]  += sixth * (a1_1[s] + 2.f * (a2_1[s] + a3_1[s]) + a4_1[s]);
        }
    }

    #pragma unroll
    for (int s = 0; s < 2; ++s) {
        int i0 = (bA + s) * D + 2 * lane;
        float2 o = make_float2(th0[s] * OUT_SCALE, th1[s] * OUT_SCALE);
        *reinterpret_cast<float2*>(&out[i0]) = o;
    }
}

extern "C" void kernel_launch(void* const* d_in, const int* in_sizes, int n_in,
                              void* d_out, int out_size, void* d_ws, size_t ws_size,
                              hipStream_t stream) {
    const float* x     = (const float*)d_in[0];
    const float* w_in  = (const float*)d_in[1];
    const float* b_in  = (const float*)d_in[2];
    const float* w0    = (const float*)d_in[3];
    const float* b0    = (const float*)d_in[4];
    const float* w1    = (const float*)d_in[5];
    const float* b1    = (const float*)d_in[6];
    const float* w_out = (const float*)d_in[7];
    const float* b_out = (const float*)d_in[8];

    float* w2buf = (float*)d_ws;                  // omega0^2/(2pi), NTOT floats
    float* cbuf  = w2buf + NTOT;                  // coupling, NTOT floats
    float* pw_in = cbuf + NTOT;                   // packed w_in, 4096
    float* pw0   = pw_in + H * NPARAMS;           // packed w0, 65536
    float* pw1   = pw0 + H * H;                   // packed w1, 65536
    float* pwo   = pw1 + H * H;                   // packed w_out, 65536
    float* out   = (float*)d_out;

    pack_kernel<<<H * H / 256, 256, 0, stream>>>(w_in, w0, w1, w_out,
                                                 pw_in, pw0, pw1, pwo);

    mlp_kernel<<<BATCH / (4 * NSS), 256, 0, stream>>>(
        x, (const float4*)pw_in, b_in, (const float4*)pw0, b0,
        (const float4*)pw1, b1, (const float4*)pwo, b_out, w2buf, cbuf);

    const int nstep = 32;
    const float dtf = (float)((59.0 / 30.0) / nstep);
    ode_kernel<<<BATCH / 8, 256, 0, stream>>>(x, w2buf, cbuf, out, nstep, dtf);
}

// Round 10
// 39.852 us; speedup vs baseline: 5.2876x; 1.8720x over previous
//
#include <hip/hip_runtime.h>
#include <math.h>

#define D 128
#define NPARAMS 16
#define H 256
#define XCOLS (D + NPARAMS)   // 144
#define BATCH 4096
#define NTOT (BATCH * D)      // 524288

#define INV_2PI_F 0.15915494309189535f
#define OUT_SCALE 2.5132741228718345f   // 2*pi / 2.5

typedef __attribute__((ext_vector_type(8))) short short8;   // 8 bf16 (4 VGPR)
typedef __attribute__((ext_vector_type(4))) float f32x4;    // MFMA acc

__device__ __forceinline__ unsigned rne16(float x) {        // fp32 -> bf16 RNE
    unsigned u = __float_as_uint(x);
    return (u + 0x7fffu + ((u >> 16) & 1u)) >> 16;
}

// ---------------- weight pre-pack into MFMA B-fragments (bf16) ---------------
// B-frag slot for (ntile t, kstep s, lane l): holds B[k][j] = W[j][k] with
// j = 16t + (l&15), k = 32s + (l>>4)*8 + e  (e = 0..7).  16 B per slot,
// slots contiguous -> mlp-side loads are coalesced dwordx4.

__global__ __launch_bounds__(256) void pack_kernel(
    const float* __restrict__ w_in, const float* __restrict__ w0,
    const float* __restrict__ w1,   const float* __restrict__ w_out,
    short8* __restrict__ pw_in, short8* __restrict__ pwb0,
    short8* __restrict__ pwb1,  short8* __restrict__ pwb2)
{
    int tid = blockIdx.x * 256 + threadIdx.x;
    if (tid < 24576) {                      // 3 matrices x 8192 slots
        const float* W = (tid < 8192) ? w0 : (tid < 16384) ? w1 : w_out;
        short8* P      = (tid < 8192) ? pwb0 : (tid < 16384) ? pwb1 : pwb2;
        int slot = tid & 8191;
        int l = slot & 63, ts = slot >> 6;
        int s = ts & 7, t = ts >> 3;
        int j = 16 * t + (l & 15);
        int kb = 32 * s + ((l >> 4) << 3);
        const float* src = W + j * H + kb;
        short8 v;
        #pragma unroll
        for (int e = 0; e < 8; ++e) v[e] = (short)rne16(src[e]);
        P[slot] = v;
    } else if (tid < 25600) {               // input layer: 1024 slots, K=16 pad
        int slot = tid - 24576;
        int l = slot & 63, t = slot >> 6;
        int j = 16 * t + (l & 15), gg = l >> 4;
        short8 v = {0, 0, 0, 0, 0, 0, 0, 0};
        if (gg < 2) {
            const float* src = w_in + j * NPARAMS + gg * 8;
            #pragma unroll
            for (int e = 0; e < 8; ++e) v[e] = (short)rne16(src[e]);
        }
        pw_in[slot] = v;
    }
}

// ---------------- MFMA MLP ---------------------------------------------------
// Block = 256 thr (4 waves) x 16 samples. Wave w owns n-tiles 4w..4w+3.
// Act buffer: LDS fp32 [16 rows][256 cols], XOR-swizzled (byte ^= (row&7)<<5)
// so A-frag reads (16 lanes @ stride 1024B) are conflict-free.

__device__ __forceinline__ short8 load_afrag(const char* actb, int li, int g, int s) {
    int byte = li * 1024 + s * 128 + g * 32;
    byte ^= (li & 7) << 5;
    float4 lo = *reinterpret_cast<const float4*>(actb + byte);
    float4 hi = *reinterpret_cast<const float4*>(actb + byte + 16);
    short8 a;
    a[0] = (short)rne16(lo.x); a[1] = (short)rne16(lo.y);
    a[2] = (short)rne16(lo.z); a[3] = (short)rne16(lo.w);
    a[4] = (short)rne16(hi.x); a[5] = (short)rne16(hi.y);
    a[6] = (short)rne16(hi.z); a[7] = (short)rne16(hi.w);
    return a;
}

__device__ __forceinline__ void hidden_layer(
    const char* actb, const short8* __restrict__ pwb,
    const float* __restrict__ bias, int lane, int li, int g, int w,
    f32x4 acc[4])
{
    short8 af[8];
    #pragma unroll
    for (int s = 0; s < 8; ++s) af[s] = load_afrag(actb, li, g, s);

    #pragma unroll
    for (int t = 0; t < 4; ++t) {
        float bb = bias[(w * 4 + t) * 16 + li];
        f32x4 tmp = {bb, bb, bb, bb};
        acc[t] = tmp;
    }
    short8 bf[4][8];
    #pragma unroll
    for (int t = 0; t < 4; ++t)
        #pragma unroll
        for (int s = 0; s < 8; ++s)
            bf[t][s] = pwb[((w * 4 + t) * 8 + s) * 64 + lane];

    #pragma unroll
    for (int s = 0; s < 8; ++s)
        #pragma unroll
        for (int t = 0; t < 4; ++t)
            acc[t] = __builtin_amdgcn_mfma_f32_16x16x32_bf16(af[s], bf[t][s], acc[t], 0, 0, 0);
}

__device__ __forceinline__ void store_act(char* actb, const f32x4 acc[4],
                                          int li, int g, int w) {
    #pragma unroll
    for (int t = 0; t < 4; ++t) {
        int col = (w * 4 + t) * 16 + li;
        #pragma unroll
        for (int r = 0; r < 4; ++r) {
            int row = g * 4 + r;
            int byte = (row * 1024 + col * 4) ^ ((row & 7) << 5);
            *reinterpret_cast<float*>(actb + byte) = fmaxf(acc[t][r], 0.f);
        }
    }
}

__global__ __launch_bounds__(256, 1) void mlp_kernel(
    const float* __restrict__ x,
    const short8* __restrict__ pw_in, const float* __restrict__ b_in,
    const short8* __restrict__ pwb0,  const float* __restrict__ bb0,
    const short8* __restrict__ pwb1,  const float* __restrict__ bb1,
    const short8* __restrict__ pwb2,  const float* __restrict__ b_out,
    float* __restrict__ w2buf, float* __restrict__ cbuf)
{
    __shared__ float act[16 * 256];   // 16 KB, swizzled fp32
    char* actb = (char*)act;
    const int lane = threadIdx.x & 63;
    const int w    = threadIdx.x >> 6;
    const int li   = lane & 15, g = lane >> 4;
    const int b0i  = blockIdx.x * 16;

    f32x4 acc[4];

    // ---- input layer: params(16, zero-padded to 32) -> 256 ----
    {
        short8 a0 = {0, 0, 0, 0, 0, 0, 0, 0};
        if (g < 2) {
            const float* xr = x + (b0i + li) * XCOLS + D + g * 8;
            #pragma unroll
            for (int e = 0; e < 8; ++e) a0[e] = (short)rne16(xr[e]);
        }
        #pragma unroll
        for (int t = 0; t < 4; ++t) {
            float bb = b_in[(w * 4 + t) * 16 + li];
            f32x4 tmp = {bb, bb, bb, bb};
            acc[t] = tmp;
            short8 bfr = pw_in[(w * 4 + t) * 64 + lane];
            acc[t] = __builtin_amdgcn_mfma_f32_16x16x32_bf16(a0, bfr, acc[t], 0, 0, 0);
        }
        store_act(actb, acc, li, g, w);
    }
    __syncthreads();

    hidden_layer(actb, pwb0, bb0, lane, li, g, w, acc);
    __syncthreads();                      // all A-reads done before overwrite
    store_act(actb, acc, li, g, w);
    __syncthreads();

    hidden_layer(actb, pwb1, bb1, lane, li, g, w, acc);
    __syncthreads();
    store_act(actb, acc, li, g, w);
    __syncthreads();

    hidden_layer(actb, pwb2, b_out, lane, li, g, w, acc);   // coef, no relu

    // ---- epilogue: j = (w*4+t)*16+li; sample b = b0i + g*4 + r ----
    #pragma unroll
    for (int t = 0; t < 4; ++t) {
        int j = (w * 4 + t) * 16 + li;
        #pragma unroll
        for (int r = 0; r < 4; ++r) {
            int b = b0i + g * 4 + r;
            float c = acc[t][r];
            if (j < D) {
                float om = fmaf(c, 1.5f, 0.5f);
                w2buf[b * D + j] = om * om * INV_2PI_F;
            } else {
                cbuf[b * D + (j - D)] = c;
            }
        }
    }
}

// ---------------- ODE: revolution-domain RK4, 2 samples per wave -------------

__device__ __forceinline__ float rot_from_lower(float v) {  // lane n <- lane (n-1)&63
    return __int_as_float(__builtin_amdgcn_mov_dpp(__float_as_int(v), 0x13C, 0xF, 0xF, false)); // wave_ror:1
}
__device__ __forceinline__ float rot_from_upper(float v) {  // lane n <- lane (n+1)&63
    return __int_as_float(__builtin_amdgcn_mov_dpp(__float_as_int(v), 0x134, 0xF, 0xF, false)); // wave_rol:1
}

__global__ __launch_bounds__(256) void ode_kernel(
    const float* __restrict__ x,
    const float* __restrict__ w2buf,
    const float* __restrict__ cbuf,
    float* __restrict__ out,
    int nstep, float dt)
{
    const int lane = threadIdx.x & 63;
    const int wid  = threadIdx.x >> 6;
    const int bA   = blockIdx.x * 8 + wid * 2;   // two consecutive samples

    float th0[2], th1[2], v0[2], v1[2];
    float nw0[2], nw1[2], c0[2], c1[2], cl[2];

    #pragma unroll
    for (int s = 0; s < 2; ++s) {
        int b  = bA + s;
        int i0 = b * D + 2 * lane;
        float2 xi  = *reinterpret_cast<const float2*>(&x[b * XCOLS + 2 * lane]);
        th0[s] = xi.x - 0.5f;            // phi0 = x - 1/2 (revolutions)
        th1[s] = xi.y - 0.5f;
        v0[s] = 0.f; v1[s] = 0.f;
        float2 w2p = *reinterpret_cast<const float2*>(&w2buf[i0]);
        float2 cp  = *reinterpret_cast<const float2*>(&cbuf[i0]);
        nw0[s] = -w2p.x; nw1[s] = -w2p.y;
        c0[s] = cp.x;    c1[s] = cp.y;
        cl[s] = cbuf[(i0 + NTOT - 1) % NTOT];   // flat-roll left coupling of osc 2l
    }

    auto deriv = [&](const float t0[2], const float t1[2], float a0[2], float a1[2]) {
        #pragma unroll
        for (int s = 0; s < 2; ++s) {
            float L0 = rot_from_lower(t1[s]);   // phi of osc 2l-1 (wraps 0 -> 127)
            float R1 = rot_from_upper(t0[s]);   // phi of osc 2l+2 (wraps 63 -> 0)
            float s0 = __builtin_amdgcn_sinf(t0[s]);   // sin(2pi*phi), raw v_sin_f32
            float s1 = __builtin_amdgcn_sinf(t1[s]);
            float dd  = t1[s] - t0[s];
            float cpl = c0[s] * dd;
            a0[s] = fmaf(s0, nw0[s], fmaf(cl[s], L0 - t0[s],  cpl));
            a1[s] = fmaf(s1, nw1[s], fmaf(c1[s], R1 - t1[s], -cpl));
        }
    };

    const float hdt   = 0.5f * dt;
    const float sixth = dt * (1.0f / 6.0f);

    for (int it = 0; it < nstep; ++it) {
        float a1_0[2], a1_1[2];
        deriv(th0, th1, a1_0, a1_1);

        float t2_0[2], t2_1[2], k2_0[2], k2_1[2];
        #pragma unroll
        for (int s = 0; s < 2; ++s) {
            t2_0[s] = fmaf(hdt, v0[s], th0[s]);   t2_1[s] = fmaf(hdt, v1[s], th1[s]);
            k2_0[s] = fmaf(hdt, a1_0[s], v0[s]);  k2_1[s] = fmaf(hdt, a1_1[s], v1[s]);
        }
        float a2_0[2], a2_1[2];
        deriv(t2_0, t2_1, a2_0, a2_1);

        float t3_0[2], t3_1[2], k3_0[2], k3_1[2];
        #pragma unroll
        for (int s = 0; s < 2; ++s) {
            t3_0[s] = fmaf(hdt, k2_0[s], th0[s]); t3_1[s] = fmaf(hdt, k2_1[s], th1[s]);
            k3_0[s] = fmaf(hdt, a2_0[s], v0[s]);  k3_1[s] = fmaf(hdt, a2_1[s], v1[s]);
        }
        float a3_0[2], a3_1[2];
        deriv(t3_0, t3_1, a3_0, a3_1);

        float t4_0[2], t4_1[2], k4_0[2], k4_1[2];
        #pragma unroll
        for (int s = 0; s < 2; ++s) {
            t4_0[s] = fmaf(dt, k3_0[s], th0[s]);  t4_1[s] = fmaf(dt, k3_1[s], th1[s]);
            k4_0[s] = fmaf(dt, a3_0[s], v0[s]);   k4_1[s] = fmaf(dt, a3_1[s], v1[s]);
        }
        float a4_0[2], a4_1[2];
        deriv(t4_0, t4_1, a4_0, a4_1);

        #pragma unroll
        for (int s = 0; s < 2; ++s) {
            th0[s] += sixth * (v0[s] + 2.f * (k2_0[s] + k3_0[s]) + k4_0[s]);
            th1[s] += sixth * (v1[s] + 2.f * (k2_1[s] + k3_1[s]) + k4_1[s]);
            v0[s]  += sixth * (a1_0[s] + 2.f * (a2_0[s] + a3_0[s]) + a4_0[s]);
            v1[s]  += sixth * (a1_1[s] + 2.f * (a2_1[s] + a3_1[s]) + a4_1[s]);
        }
    }

    #pragma unroll
    for (int s = 0; s < 2; ++s) {
        int i0 = (bA + s) * D + 2 * lane;
        float2 o = make_float2(th0[s] * OUT_SCALE, th1[s] * OUT_SCALE);
        *reinterpret_cast<float2*>(&out[i0]) = o;
    }
}

extern "C" void kernel_launch(void* const* d_in, const int* in_sizes, int n_in,
                              void* d_out, int out_size, void* d_ws, size_t ws_size,
                              hipStream_t stream) {
    const float* x     = (const float*)d_in[0];
    const float* w_in  = (const float*)d_in[1];
    const float* b_in  = (const float*)d_in[2];
    const float* w0    = (const float*)d_in[3];
    const float* b0    = (const float*)d_in[4];
    const float* w1    = (const float*)d_in[5];
    const float* b1    = (const float*)d_in[6];
    const float* w_out = (const float*)d_in[7];
    const float* b_out = (const float*)d_in[8];

    float* w2buf = (float*)d_ws;                  // omega0^2/(2pi), NTOT floats
    float* cbuf  = w2buf + NTOT;                  // coupling, NTOT floats
    short8* pw_in = (short8*)(cbuf + NTOT);       // 1024 slots x 16 B
    short8* pwb0  = pw_in + 1024;                 // 8192 slots
    short8* pwb1  = pwb0 + 8192;
    short8* pwb2  = pwb1 + 8192;
    float* out   = (float*)d_out;

    pack_kernel<<<100, 256, 0, stream>>>(w_in, w0, w1, w_out,
                                         pw_in, pwb0, pwb1, pwb2);

    mlp_kernel<<<BATCH / 16, 256, 0, stream>>>(
        x, pw_in, b_in, pwb0, b0, pwb1, b1, pwb2, b_out, w2buf, cbuf);

    const int nstep = 32;
    const float dtf = (float)((59.0 / 30.0) / nstep);
    ode_kernel<<<BATCH / 8, 256, 0, stream>>>(x, w2buf, cbuf, out, nstep, dtf);
}

// Round 11
// 30.863 us; speedup vs baseline: 6.8276x; 1.2913x over previous
//
#include <hip/hip_runtime.h>
#include <math.h>

#define D 128
#define NPARAMS 16
#define H 256
#define XCOLS (D + NPARAMS)   // 144
#define BATCH 4096
#define NTOT (BATCH * D)      // 524288

#define INV_2PI_F 0.15915494309189535f
#define OUT_SCALE 2.5132741228718345f   // 2*pi / 2.5

typedef __attribute__((ext_vector_type(8))) short short8;   // 8 bf16 (4 VGPR)
typedef __attribute__((ext_vector_type(4))) float f32x4;    // MFMA acc

__device__ __forceinline__ unsigned rne16(float x) {        // fp32 -> bf16 RNE
    unsigned u = __float_as_uint(x);
    return (u + 0x7fffu + ((u >> 16) & 1u)) >> 16;
}

// ---------------- weight pre-pack into MFMA B-fragments (bf16) ---------------
// B-frag slot for (ntile t, kstep s, lane l): holds B[k][j] = W[j][k] with
// j = 16t + (l&15), k = 32s + (l>>4)*8 + e  (e = 0..7).

__global__ __launch_bounds__(256) void pack_kernel(
    const float* __restrict__ w_in, const float* __restrict__ w0,
    const float* __restrict__ w1,   const float* __restrict__ w_out,
    short8* __restrict__ pw_in, short8* __restrict__ pwb0,
    short8* __restrict__ pwb1,  short8* __restrict__ pwb2)
{
    int tid = blockIdx.x * 256 + threadIdx.x;
    if (tid < 24576) {                      // 3 matrices x 8192 slots
        const float* W = (tid < 8192) ? w0 : (tid < 16384) ? w1 : w_out;
        short8* P      = (tid < 8192) ? pwb0 : (tid < 16384) ? pwb1 : pwb2;
        int slot = tid & 8191;
        int l = slot & 63, ts = slot >> 6;
        int s = ts & 7, t = ts >> 3;
        int j = 16 * t + (l & 15);
        int kb = 32 * s + ((l >> 4) << 3);
        const float* src = W + j * H + kb;
        short8 v;
        #pragma unroll
        for (int e = 0; e < 8; ++e) v[e] = (short)rne16(src[e]);
        P[slot] = v;
    } else if (tid < 25600) {               // input layer: 1024 slots, K=16 pad
        int slot = tid - 24576;
        int l = slot & 63, t = slot >> 6;
        int j = 16 * t + (l & 15), gg = l >> 4;
        short8 v = {0, 0, 0, 0, 0, 0, 0, 0};
        if (gg < 2) {
            const float* src = w_in + j * NPARAMS + gg * 8;
            #pragma unroll
            for (int e = 0; e < 8; ++e) v[e] = (short)rne16(src[e]);
        }
        pw_in[slot] = v;
    }
}

// ---------------- MFMA MLP ---------------------------------------------------
// Block = 256 thr (4 waves) x 16 samples. Wave w owns n-tiles 4w..4w+3.
// Act: TWO 16 KB fp32 LDS buffers (ping/pong) -> ONE sync per layer.
// XOR swizzle (byte ^= (row&7)<<5) kills the 16-way stride-1024 conflict.

__device__ __forceinline__ short8 load_afrag(const char* actb, int li, int g, int s) {
    int byte = li * 1024 + s * 128 + g * 32;
    byte ^= (li & 7) << 5;
    float4 lo = *reinterpret_cast<const float4*>(actb + byte);
    float4 hi = *reinterpret_cast<const float4*>(actb + byte + 16);
    short8 a;
    a[0] = (short)rne16(lo.x); a[1] = (short)rne16(lo.y);
    a[2] = (short)rne16(lo.z); a[3] = (short)rne16(lo.w);
    a[4] = (short)rne16(hi.x); a[5] = (short)rne16(hi.y);
    a[6] = (short)rne16(hi.z); a[7] = (short)rne16(hi.w);
    return a;
}

__device__ __forceinline__ void hidden_layer(
    const char* actb, const short8* __restrict__ pwb,
    const float* __restrict__ bias, int lane, int li, int g, int w,
    f32x4 acc[4])
{
    short8 af[8];
    #pragma unroll
    for (int s = 0; s < 8; ++s) af[s] = load_afrag(actb, li, g, s);

    #pragma unroll
    for (int t = 0; t < 4; ++t) {
        float bb = bias[(w * 4 + t) * 16 + li];
        f32x4 tmp = {bb, bb, bb, bb};
        acc[t] = tmp;
    }
    short8 bf[4][8];
    #pragma unroll
    for (int t = 0; t < 4; ++t)
        #pragma unroll
        for (int s = 0; s < 8; ++s)
            bf[t][s] = pwb[((w * 4 + t) * 8 + s) * 64 + lane];

    #pragma unroll
    for (int s = 0; s < 8; ++s)
        #pragma unroll
        for (int t = 0; t < 4; ++t)
            acc[t] = __builtin_amdgcn_mfma_f32_16x16x32_bf16(af[s], bf[t][s], acc[t], 0, 0, 0);
}

__device__ __forceinline__ void store_act(char* actb, const f32x4 acc[4],
                                          int li, int g, int w) {
    #pragma unroll
    for (int t = 0; t < 4; ++t) {
        int col = (w * 4 + t) * 16 + li;
        #pragma unroll
        for (int r = 0; r < 4; ++r) {
            int row = g * 4 + r;
            int byte = (row * 1024 + col * 4) ^ ((row & 7) << 5);
            *reinterpret_cast<float*>(actb + byte) = fmaxf(acc[t][r], 0.f);
        }
    }
}

__global__ __launch_bounds__(256, 1) void mlp_kernel(
    const float* __restrict__ x,
    const short8* __restrict__ pw_in, const float* __restrict__ b_in,
    const short8* __restrict__ pwb0,  const float* __restrict__ bb0,
    const short8* __restrict__ pwb1,  const float* __restrict__ bb1,
    const short8* __restrict__ pwb2,  const float* __restrict__ b_out,
    float* __restrict__ w2buf, float* __restrict__ cbuf)
{
    __shared__ float act[2][16 * 256];   // 2 x 16 KB ping/pong, swizzled fp32
    char* bufA = (char*)&act[0][0];
    char* bufB = (char*)&act[1][0];
    const int lane = threadIdx.x & 63;
    const int w    = threadIdx.x >> 6;
    const int li   = lane & 15, g = lane >> 4;
    const int b0i  = blockIdx.x * 16;

    f32x4 acc[4];

    // ---- input layer: params(16, zero-padded to 32) -> 256 -> bufA ----
    {
        short8 a0 = {0, 0, 0, 0, 0, 0, 0, 0};
        if (g < 2) {
            const float* xr = x + (b0i + li) * XCOLS + D + g * 8;
            #pragma unroll
            for (int e = 0; e < 8; ++e) a0[e] = (short)rne16(xr[e]);
        }
        #pragma unroll
        for (int t = 0; t < 4; ++t) {
            float bb = b_in[(w * 4 + t) * 16 + li];
            f32x4 tmp = {bb, bb, bb, bb};
            acc[t] = tmp;
            short8 bfr = pw_in[(w * 4 + t) * 64 + lane];
            acc[t] = __builtin_amdgcn_mfma_f32_16x16x32_bf16(a0, bfr, acc[t], 0, 0, 0);
        }
        store_act(bufA, acc, li, g, w);
    }
    __syncthreads();

    hidden_layer(bufA, pwb0, bb0, lane, li, g, w, acc);   // read A
    store_act(bufB, acc, li, g, w);                       // write B
    __syncthreads();

    hidden_layer(bufB, pwb1, bb1, lane, li, g, w, acc);   // read B
    store_act(bufA, acc, li, g, w);                       // write A
    __syncthreads();

    hidden_layer(bufA, pwb2, b_out, lane, li, g, w, acc); // coef, no relu

    // ---- epilogue: j = (w*4+t)*16+li; sample b = b0i + g*4 + r ----
    #pragma unroll
    for (int t = 0; t < 4; ++t) {
        int j = (w * 4 + t) * 16 + li;
        #pragma unroll
        for (int r = 0; r < 4; ++r) {
            int b = b0i + g * 4 + r;
            float c = acc[t][r];
            if (j < D) {
                float om = fmaf(c, 1.5f, 0.5f);
                w2buf[b * D + j] = om * om * INV_2PI_F;
            } else {
                cbuf[b * D + (j - D)] = c;
            }
        }
    }
}

// ---------------- ODE: revolution-domain RK4, 2 samples per wave -------------

__device__ __forceinline__ float rot_from_lower(float v) {  // lane n <- lane (n-1)&63
    return __int_as_float(__builtin_amdgcn_mov_dpp(__float_as_int(v), 0x13C, 0xF, 0xF, false)); // wave_ror:1
}
__device__ __forceinline__ float rot_from_upper(float v) {  // lane n <- lane (n+1)&63
    return __int_as_float(__builtin_amdgcn_mov_dpp(__float_as_int(v), 0x134, 0xF, 0xF, false)); // wave_rol:1
}

__global__ __launch_bounds__(256) void ode_kernel(
    const float* __restrict__ x,
    const float* __restrict__ w2buf,
    const float* __restrict__ cbuf,
    float* __restrict__ out,
    int nstep, float dt)
{
    const int lane = threadIdx.x & 63;
    const int wid  = threadIdx.x >> 6;
    const int bA   = blockIdx.x * 8 + wid * 2;   // two consecutive samples

    float th0[2], th1[2], v0[2], v1[2];
    float nw0[2], nw1[2], c0[2], c1[2], cl[2];

    #pragma unroll
    for (int s = 0; s < 2; ++s) {
        int b  = bA + s;
        int i0 = b * D + 2 * lane;
        float2 xi  = *reinterpret_cast<const float2*>(&x[b * XCOLS + 2 * lane]);
        th0[s] = xi.x - 0.5f;            // phi0 = x - 1/2 (revolutions)
        th1[s] = xi.y - 0.5f;
        v0[s] = 0.f; v1[s] = 0.f;
        float2 w2p = *reinterpret_cast<const float2*>(&w2buf[i0]);
        float2 cp  = *reinterpret_cast<const float2*>(&cbuf[i0]);
        nw0[s] = -w2p.x; nw1[s] = -w2p.y;
        c0[s] = cp.x;    c1[s] = cp.y;
        cl[s] = cbuf[(i0 + NTOT - 1) % NTOT];   // flat-roll left coupling of osc 2l
    }

    auto deriv = [&](const float t0[2], const float t1[2], float a0[2], float a1[2]) {
        #pragma unroll
        for (int s = 0; s < 2; ++s) {
            float L0 = rot_from_lower(t1[s]);   // phi of osc 2l-1 (wraps 0 -> 127)
            float R1 = rot_from_upper(t0[s]);   // phi of osc 2l+2 (wraps 63 -> 0)
            float s0 = __builtin_amdgcn_sinf(t0[s]);   // sin(2pi*phi), raw v_sin_f32
            float s1 = __builtin_amdgcn_sinf(t1[s]);
            float dd  = t1[s] - t0[s];
            float cpl = c0[s] * dd;
            a0[s] = fmaf(s0, nw0[s], fmaf(cl[s], L0 - t0[s],  cpl));
            a1[s] = fmaf(s1, nw1[s], fmaf(c1[s], R1 - t1[s], -cpl));
        }
    };

    const float hdt   = 0.5f * dt;
    const float sixth = dt * (1.0f / 6.0f);

    for (int it = 0; it < nstep; ++it) {
        float a1_0[2], a1_1[2];
        deriv(th0, th1, a1_0, a1_1);

        float t2_0[2], t2_1[2], k2_0[2], k2_1[2];
        #pragma unroll
        for (int s = 0; s < 2; ++s) {
            t2_0[s] = fmaf(hdt, v0[s], th0[s]);   t2_1[s] = fmaf(hdt, v1[s], th1[s]);
            k2_0[s] = fmaf(hdt, a1_0[s], v0[s]);  k2_1[s] = fmaf(hdt, a1_1[s], v1[s]);
        }
        float a2_0[2], a2_1[2];
        deriv(t2_0, t2_1, a2_0, a2_1);

        float t3_0[2], t3_1[2], k3_0[2], k3_1[2];
        #pragma unroll
        for (int s = 0; s < 2; ++s) {
            t3_0[s] = fmaf(hdt, k2_0[s], th0[s]); t3_1[s] = fmaf(hdt, k2_1[s], th1[s]);
            k3_0[s] = fmaf(hdt, a2_0[s], v0[s]);  k3_1[s] = fmaf(hdt, a2_1[s], v1[s]);
        }
        float a3_0[2], a3_1[2];
        deriv(t3_0, t3_1, a3_0, a3_1);

        float t4_0[2], t4_1[2], k4_0[2], k4_1[2];
        #pragma unroll
        for (int s = 0; s < 2; ++s) {
            t4_0[s] = fmaf(dt, k3_0[s], th0[s]);  t4_1[s] = fmaf(dt, k3_1[s], th1[s]);
            k4_0[s] = fmaf(dt, a3_0[s], v0[s]);   k4_1[s] = fmaf(dt, a3_1[s], v1[s]);
        }
        float a4_0[2], a4_1[2];
        deriv(t4_0, t4_1, a4_0, a4_1);

        #pragma unroll
        for (int s = 0; s < 2; ++s) {
            th0[s] += sixth * (v0[s] + 2.f * (k2_0[s] + k3_0[s]) + k4_0[s]);
            th1[s] += sixth * (v1[s] + 2.f * (k2_1[s] + k3_1[s]) + k4_1[s]);
            v0[s]  += sixth * (a1_0[s] + 2.f * (a2_0[s] + a3_0[s]) + a4_0[s]);
            v1[s]  += sixth * (a1_1[s] + 2.f * (a2_1[s] + a3_1[s]) + a4_1[s]);
        }
    }

    #pragma unroll
    for (int s = 0; s < 2; ++s) {
        int i0 = (bA + s) * D + 2 * lane;
        float2 o = make_float2(th0[s] * OUT_SCALE, th1[s] * OUT_SCALE);
        *reinterpret_cast<float2*>(&out[i0]) = o;
    }
}

extern "C" void kernel_launch(void* const* d_in, const int* in_sizes, int n_in,
                              void* d_out, int out_size, void* d_ws, size_t ws_size,
                              hipStream_t stream) {
    const float* x     = (const float*)d_in[0];
    const float* w_in  = (const float*)d_in[1];
    const float* b_in  = (const float*)d_in[2];
    const float* w0    = (const float*)d_in[3];
    const float* b0    = (const float*)d_in[4];
    const float* w1    = (const float*)d_in[5];
    const float* b1    = (const float*)d_in[6];
    const float* w_out = (const float*)d_in[7];
    const float* b_out = (const float*)d_in[8];

    float* w2buf = (float*)d_ws;                  // omega0^2/(2pi), NTOT floats
    float* cbuf  = w2buf + NTOT;                  // coupling, NTOT floats
    short8* pw_in = (short8*)(cbuf + NTOT);       // 1024 slots x 16 B
    short8* pwb0  = pw_in + 1024;                 // 8192 slots
    short8* pwb1  = pwb0 + 8192;
    short8* pwb2  = pwb1 + 8192;
    float* out   = (float*)d_out;

    pack_kernel<<<100, 256, 0, stream>>>(w_in, w0, w1, w_out,
                                         pw_in, pwb0, pwb1, pwb2);

    mlp_kernel<<<BATCH / 16, 256, 0, stream>>>(
        x, pw_in, b_in, pwb0, b0, pwb1, b1, pwb2, b_out, w2buf, cbuf);

    const int nstep = 16;
    const float dtf = (float)((59.0 / 30.0) / nstep);
    ode_kernel<<<BATCH / 8, 256, 0, stream>>>(x, w2buf, cbuf, out, nstep, dtf);
}

// Round 12
// 27.902 us; speedup vs baseline: 7.5521x; 1.1061x over previous
//
#include <hip/hip_runtime.h>
#include <math.h>

#define D 128
#define NPARAMS 16
#define H 256
#define XCOLS (D + NPARAMS)   // 144
#define BATCH 4096
#define NTOT (BATCH * D)      // 524288

#define INV_2PI_F 0.15915494309189535f
#define OUT_SCALE 2.5132741228718345f   // 2*pi / 2.5

typedef __attribute__((ext_vector_type(8))) short short8;   // 8 bf16 (4 VGPR)
typedef __attribute__((ext_vector_type(4))) float f32x4;    // MFMA acc

__device__ __forceinline__ unsigned rne16(float x) {        // fp32 -> bf16 RNE
    unsigned u = __float_as_uint(x);
    return (u + 0x7fffu + ((u >> 16) & 1u)) >> 16;
}

// ---------------- weight pre-pack into MFMA B-fragments (bf16) ---------------
// B-frag slot (ntile t, kstep s, lane l): B[k][j] = W[j][k],
// j = 16t + (l&15), k = 32s + (l>>4)*8 + e.

__global__ __launch_bounds__(256) void pack_kernel(
    const float* __restrict__ w_in, const float* __restrict__ w0,
    const float* __restrict__ w1,   const float* __restrict__ w_out,
    short8* __restrict__ pw_in, short8* __restrict__ pwb0,
    short8* __restrict__ pwb1,  short8* __restrict__ pwb2)
{
    int tid = blockIdx.x * 256 + threadIdx.x;
    if (tid < 24576) {                      // 3 matrices x 8192 slots
        const float* W = (tid < 8192) ? w0 : (tid < 16384) ? w1 : w_out;
        short8* P      = (tid < 8192) ? pwb0 : (tid < 16384) ? pwb1 : pwb2;
        int slot = tid & 8191;
        int l = slot & 63, ts = slot >> 6;
        int s = ts & 7, t = ts >> 3;
        int j = 16 * t + (l & 15);
        int kb = 32 * s + ((l >> 4) << 3);
        const float* src = W + j * H + kb;
        short8 v;
        #pragma unroll
        for (int e = 0; e < 8; ++e) v[e] = (short)rne16(src[e]);
        P[slot] = v;
    } else if (tid < 25600) {               // input layer: 1024 slots, K=16 pad
        int slot = tid - 24576;
        int l = slot & 63, t = slot >> 6;
        int j = 16 * t + (l & 15), gg = l >> 4;
        short8 v = {0, 0, 0, 0, 0, 0, 0, 0};
        if (gg < 2) {
            const float* src = w_in + j * NPARAMS + gg * 8;
            #pragma unroll
            for (int e = 0; e < 8; ++e) v[e] = (short)rne16(src[e]);
        }
        pw_in[slot] = v;
    }
}

// ---------------- MFMA MLP ---------------------------------------------------
// Block = 512 thr (8 waves) x 16 samples; wave w owns n-tiles 2w, 2w+1.
// Activations live in LDS as BF16 [16 samples][256 feats] (512 B row stride,
// XOR swizzle byte ^= (row&7)<<4): A-frag load = one ds_read_b128, zero cvt.
// grid = 256 blocks -> 1 block/CU, 2 waves/SIMD.

__device__ __forceinline__ int act_addr(int row, int colbyte) {
    return (row * 512 + colbyte) ^ ((row & 7) << 4);
}

__device__ __forceinline__ short8 load_afrag16(const char* actb, int li, int g, int s) {
    return *reinterpret_cast<const short8*>(actb + act_addr(li, s * 64 + g * 16));
}

__device__ __forceinline__ void store_act16(char* actb, const f32x4 acc[2],
                                            int li, int g, int w, bool relu) {
    #pragma unroll
    for (int t = 0; t < 2; ++t) {
        int col = (2 * w + t) * 16 + li;
        #pragma unroll
        for (int r = 0; r < 4; ++r) {
            int row = g * 4 + r;
            float v = relu ? fmaxf(acc[t][r], 0.f) : acc[t][r];
            *reinterpret_cast<short*>(actb + act_addr(row, col * 2)) = (short)rne16(v);
        }
    }
}

__device__ __forceinline__ void hidden_layer16(
    const char* actb, const short8* __restrict__ pwb,
    const float* __restrict__ bias, int lane, int li, int g, int w,
    f32x4 acc[2])
{
    short8 bf[2][8];
    #pragma unroll
    for (int t = 0; t < 2; ++t)
        #pragma unroll
        for (int s = 0; s < 8; ++s)
            bf[t][s] = pwb[((2 * w + t) * 8 + s) * 64 + lane];

    short8 af[8];
    #pragma unroll
    for (int s = 0; s < 8; ++s) af[s] = load_afrag16(actb, li, g, s);

    #pragma unroll
    for (int t = 0; t < 2; ++t) {
        float bb = bias[(2 * w + t) * 16 + li];
        f32x4 tmp = {bb, bb, bb, bb};
        acc[t] = tmp;
    }
    #pragma unroll
    for (int s = 0; s < 8; ++s)
        #pragma unroll
        for (int t = 0; t < 2; ++t)
            acc[t] = __builtin_amdgcn_mfma_f32_16x16x32_bf16(af[s], bf[t][s], acc[t], 0, 0, 0);
}

__global__ __launch_bounds__(512, 1) void mlp_kernel(
    const float* __restrict__ x,
    const short8* __restrict__ pw_in, const float* __restrict__ b_in,
    const short8* __restrict__ pwb0,  const float* __restrict__ bb0,
    const short8* __restrict__ pwb1,  const float* __restrict__ bb1,
    const short8* __restrict__ pwb2,  const float* __restrict__ b_out,
    float* __restrict__ w2buf, float* __restrict__ cbuf)
{
    __shared__ short act[2][16 * 256];   // 2 x 8 KB bf16, swizzled
    char* bufA = (char*)&act[0][0];
    char* bufB = (char*)&act[1][0];
    const int lane = threadIdx.x & 63;
    const int w    = threadIdx.x >> 6;      // 0..7
    const int li   = lane & 15, g = lane >> 4;
    const int b0i  = blockIdx.x * 16;

    f32x4 acc[2];

    // ---- input layer: params(16, zero-padded to 32) -> 256 -> bufA ----
    {
        short8 a0 = {0, 0, 0, 0, 0, 0, 0, 0};
        if (g < 2) {
            const float* xr = x + (b0i + li) * XCOLS + D + g * 8;
            #pragma unroll
            for (int e = 0; e < 8; ++e) a0[e] = (short)rne16(xr[e]);
        }
        #pragma unroll
        for (int t = 0; t < 2; ++t) {
            float bb = b_in[(2 * w + t) * 16 + li];
            f32x4 tmp = {bb, bb, bb, bb};
            acc[t] = tmp;
            short8 bfr = pw_in[(2 * w + t) * 64 + lane];
            acc[t] = __builtin_amdgcn_mfma_f32_16x16x32_bf16(a0, bfr, acc[t], 0, 0, 0);
        }
        store_act16(bufA, acc, li, g, w, true);
    }
    __syncthreads();

    hidden_layer16(bufA, pwb0, bb0, lane, li, g, w, acc);   // read A
    store_act16(bufB, acc, li, g, w, true);                 // write B
    __syncthreads();

    hidden_layer16(bufB, pwb1, bb1, lane, li, g, w, acc);   // read B
    store_act16(bufA, acc, li, g, w, true);                 // write A
    __syncthreads();

    hidden_layer16(bufA, pwb2, b_out, lane, li, g, w, acc); // coef, no relu

    // ---- epilogue: j = (2w+t)*16+li; sample b = b0i + g*4 + r ----
    #pragma unroll
    for (int t = 0; t < 2; ++t) {
        int j = (2 * w + t) * 16 + li;
        #pragma unroll
        for (int r = 0; r < 4; ++r) {
            int b = b0i + g * 4 + r;
            float c = acc[t][r];
            if (j < D) {
                float om = fmaf(c, 1.5f, 0.5f);
                w2buf[b * D + j] = om * om * INV_2PI_F;
            } else {
                cbuf[b * D + (j - D)] = c;
            }
        }
    }
}

// ---------------- ODE: revolution-domain RK4, 2 samples per wave -------------

__device__ __forceinline__ float rot_from_lower(float v) {  // lane n <- lane (n-1)&63
    return __int_as_float(__builtin_amdgcn_mov_dpp(__float_as_int(v), 0x13C, 0xF, 0xF, false)); // wave_ror:1
}
__device__ __forceinline__ float rot_from_upper(float v) {  // lane n <- lane (n+1)&63
    return __int_as_float(__builtin_amdgcn_mov_dpp(__float_as_int(v), 0x134, 0xF, 0xF, false)); // wave_rol:1
}

__global__ __launch_bounds__(256) void ode_kernel(
    const float* __restrict__ x,
    const float* __restrict__ w2buf,
    const float* __restrict__ cbuf,
    float* __restrict__ out,
    int nstep, float dt)
{
    const int lane = threadIdx.x & 63;
    const int wid  = threadIdx.x >> 6;
    const int bA   = blockIdx.x * 8 + wid * 2;   // two consecutive samples

    float th0[2], th1[2], v0[2], v1[2];
    float nw0[2], nw1[2], c0[2], c1[2], cl[2];

    #pragma unroll
    for (int s = 0; s < 2; ++s) {
        int b  = bA + s;
        int i0 = b * D + 2 * lane;
        float2 xi  = *reinterpret_cast<const float2*>(&x[b * XCOLS + 2 * lane]);
        th0[s] = xi.x - 0.5f;            // phi0 = x - 1/2 (revolutions)
        th1[s] = xi.y - 0.5f;
        v0[s] = 0.f; v1[s] = 0.f;
        float2 w2p = *reinterpret_cast<const float2*>(&w2buf[i0]);
        float2 cp  = *reinterpret_cast<const float2*>(&cbuf[i0]);
        nw0[s] = -w2p.x; nw1[s] = -w2p.y;
        c0[s] = cp.x;    c1[s] = cp.y;
        cl[s] = cbuf[(i0 + NTOT - 1) % NTOT];   // flat-roll left coupling of osc 2l
    }

    auto deriv = [&](const float t0[2], const float t1[2], float a0[2], float a1[2]) {
        #pragma unroll
        for (int s = 0; s < 2; ++s) {
            float L0 = rot_from_lower(t1[s]);   // phi of osc 2l-1 (wraps 0 -> 127)
            float R1 = rot_from_upper(t0[s]);   // phi of osc 2l+2 (wraps 63 -> 0)
            float s0 = __builtin_amdgcn_sinf(t0[s]);   // sin(2pi*phi), raw v_sin_f32
            float s1 = __builtin_amdgcn_sinf(t1[s]);
            float dd  = t1[s] - t0[s];
            float cpl = c0[s] * dd;
            a0[s] = fmaf(s0, nw0[s], fmaf(cl[s], L0 - t0[s],  cpl));
            a1[s] = fmaf(s1, nw1[s], fmaf(c1[s], R1 - t1[s], -cpl));
        }
    };

    const float hdt   = 0.5f * dt;
    const float sixth = dt * (1.0f / 6.0f);

    for (int it = 0; it < nstep; ++it) {
        float a1_0[2], a1_1[2];
        deriv(th0, th1, a1_0, a1_1);

        float t2_0[2], t2_1[2], k2_0[2], k2_1[2];
        #pragma unroll
        for (int s = 0; s < 2; ++s) {
            t2_0[s] = fmaf(hdt, v0[s], th0[s]);   t2_1[s] = fmaf(hdt, v1[s], th1[s]);
            k2_0[s] = fmaf(hdt, a1_0[s], v0[s]);  k2_1[s] = fmaf(hdt, a1_1[s], v1[s]);
        }
        float a2_0[2], a2_1[2];
        deriv(t2_0, t2_1, a2_0, a2_1);

        float t3_0[2], t3_1[2], k3_0[2], k3_1[2];
        #pragma unroll
        for (int s = 0; s < 2; ++s) {
            t3_0[s] = fmaf(hdt, k2_0[s], th0[s]); t3_1[s] = fmaf(hdt, k2_1[s], th1[s]);
            k3_0[s] = fmaf(hdt, a2_0[s], v0[s]);  k3_1[s] = fmaf(hdt, a2_1[s], v1[s]);
        }
        float a3_0[2], a3_1[2];
        deriv(t3_0, t3_1, a3_0, a3_1);

        float t4_0[2], t4_1[2], k4_0[2], k4_1[2];
        #pragma unroll
        for (int s = 0; s < 2; ++s) {
            t4_0[s] = fmaf(dt, k3_0[s], th0[s]);  t4_1[s] = fmaf(dt, k3_1[s], th1[s]);
            k4_0[s] = fmaf(dt, a3_0[s], v0[s]);   k4_1[s] = fmaf(dt, a3_1[s], v1[s]);
        }
        float a4_0[2], a4_1[2];
        deriv(t4_0, t4_1, a4_0, a4_1);

        #pragma unroll
        for (int s = 0; s < 2; ++s) {
            th0[s] += sixth * (v0[s] + 2.f * (k2_0[s] + k3_0[s]) + k4_0[s]);
            th1[s] += sixth * (v1[s] + 2.f * (k2_1[s] + k3_1[s]) + k4_1[s]);
            v0[s]  += sixth * (a1_0[s] + 2.f * (a2_0[s] + a3_0[s]) + a4_0[s]);
            v1[s]  += sixth * (a1_1[s] + 2.f * (a2_1[s] + a3_1[s]) + a4_1[s]);
        }
    }

    #pragma unroll
    for (int s = 0; s < 2; ++s) {
        int i0 = (bA + s) * D + 2 * lane;
        float2 o = make_float2(th0[s] * OUT_SCALE, th1[s] * OUT_SCALE);
        *reinterpret_cast<float2*>(&out[i0]) = o;
    }
}

extern "C" void kernel_launch(void* const* d_in, const int* in_sizes, int n_in,
                              void* d_out, int out_size, void* d_ws, size_t ws_size,
                              hipStream_t stream) {
    const float* x     = (const float*)d_in[0];
    const float* w_in  = (const float*)d_in[1];
    const float* b_in  = (const float*)d_in[2];
    const float* w0    = (const float*)d_in[3];
    const float* b0    = (const float*)d_in[4];
    const float* w1    = (const float*)d_in[5];
    const float* b1    = (const float*)d_in[6];
    const float* w_out = (const float*)d_in[7];
    const float* b_out = (const float*)d_in[8];

    float* w2buf = (float*)d_ws;                  // omega0^2/(2pi), NTOT floats
    float* cbuf  = w2buf + NTOT;                  // coupling, NTOT floats
    short8* pw_in = (short8*)(cbuf + NTOT);       // 1024 slots x 16 B
    short8* pwb0  = pw_in + 1024;                 // 8192 slots
    short8* pwb1  = pwb0 + 8192;
    short8* pwb2  = pwb1 + 8192;
    float* out   = (float*)d_out;

    pack_kernel<<<100, 256, 0, stream>>>(w_in, w0, w1, w_out,
                                         pw_in, pwb0, pwb1, pwb2);

    mlp_kernel<<<BATCH / 16, 512, 0, stream>>>(
        x, pw_in, b_in, pwb0, b0, pwb1, b1, pwb2, b_out, w2buf, cbuf);

    const int nstep = 12;
    const float dtf = (float)((59.0 / 30.0) / nstep);
    ode_kernel<<<BATCH / 8, 256, 0, stream>>>(x, w2buf, cbuf, out, nstep, dtf);
}

// Round 13
// 24.199 us; speedup vs baseline: 8.7080x; 1.1531x over previous
//
#include <hip/hip_runtime.h>
#include <math.h>

#define D 128
#define NPARAMS 16
#define H 256
#define XCOLS (D + NPARAMS)   // 144
#define BATCH 4096
#define NTOT (BATCH * D)      // 524288

#define INV_2PI_F 0.15915494309189535f
#define OUT_SCALE 2.5132741228718345f   // 2*pi / 2.5

typedef __attribute__((ext_vector_type(8))) short short8;   // 8 bf16 (4 VGPR)
typedef __attribute__((ext_vector_type(4))) float f32x4;    // MFMA acc

__device__ __forceinline__ unsigned rne16(float x) {        // fp32 -> bf16 RNE
    unsigned u = __float_as_uint(x);
    return (u + 0x7fffu + ((u >> 16) & 1u)) >> 16;
}

// ---------------- weight pre-pack into MFMA B-fragments (bf16) ---------------
// B-frag slot (ntile t, kstep s, lane l): B[k][j] = W[j][k],
// j = 16t + (l&15), k = 32s + (l>>4)*8 + e.

__global__ __launch_bounds__(256) void pack_kernel(
    const float* __restrict__ w_in, const float* __restrict__ w0,
    const float* __restrict__ w1,   const float* __restrict__ w_out,
    short8* __restrict__ pw_in, short8* __restrict__ pwb0,
    short8* __restrict__ pwb1,  short8* __restrict__ pwb2)
{
    int tid = blockIdx.x * 256 + threadIdx.x;
    if (tid < 24576) {                      // 3 matrices x 8192 slots
        const float* W = (tid < 8192) ? w0 : (tid < 16384) ? w1 : w_out;
        short8* P      = (tid < 8192) ? pwb0 : (tid < 16384) ? pwb1 : pwb2;
        int slot = tid & 8191;
        int l = slot & 63, ts = slot >> 6;
        int s = ts & 7, t = ts >> 3;
        int j = 16 * t + (l & 15);
        int kb = 32 * s + ((l >> 4) << 3);
        const float* src = W + j * H + kb;
        short8 v;
        #pragma unroll
        for (int e = 0; e < 8; ++e) v[e] = (short)rne16(src[e]);
        P[slot] = v;
    } else if (tid < 25600) {               // input layer: 1024 slots, K=16 pad
        int slot = tid - 24576;
        int l = slot & 63, t = slot >> 6;
        int j = 16 * t + (l & 15), gg = l >> 4;
        short8 v = {0, 0, 0, 0, 0, 0, 0, 0};
        if (gg < 2) {
            const float* src = w_in + j * NPARAMS + gg * 8;
            #pragma unroll
            for (int e = 0; e < 8; ++e) v[e] = (short)rne16(src[e]);
        }
        pw_in[slot] = v;
    }
}

// ---------------- MFMA MLP, software-pipelined B-fragments -------------------
// Block = 512 thr (8 waves) x 16 samples; wave w owns n-tiles 2w, 2w+1.
// Acts in LDS as bf16 [16][256] (512 B rows, XOR swizzle byte ^= (row&7)<<4).
// Layer n+1's 16 B-frag loads are issued BEFORE layer n's barrier so their
// L2 latency drains under store/barrier/A-reads/MFMA of the previous layer.

__device__ __forceinline__ int act_addr(int row, int colbyte) {
    return (row * 512 + colbyte) ^ ((row & 7) << 4);
}

__device__ __forceinline__ short8 load_afrag16(const char* actb, int li, int g, int s) {
    return *reinterpret_cast<const short8*>(actb + act_addr(li, s * 64 + g * 16));
}

__device__ __forceinline__ void store_act16(char* actb, const f32x4 acc[2],
                                            int li, int g, int w, bool relu) {
    #pragma unroll
    for (int t = 0; t < 2; ++t) {
        int col = (2 * w + t) * 16 + li;
        #pragma unroll
        for (int r = 0; r < 4; ++r) {
            int row = g * 4 + r;
            float v = relu ? fmaxf(acc[t][r], 0.f) : acc[t][r];
            *reinterpret_cast<short*>(actb + act_addr(row, col * 2)) = (short)rne16(v);
        }
    }
}

__device__ __forceinline__ void hidden_compute(
    const char* actb, const short8 (&bf)[2][8], const float bias[2],
    int li, int g, f32x4 acc[2])
{
    short8 af[8];
    #pragma unroll
    for (int s = 0; s < 8; ++s) af[s] = load_afrag16(actb, li, g, s);
    #pragma unroll
    for (int t = 0; t < 2; ++t) {
        f32x4 tmp = {bias[t], bias[t], bias[t], bias[t]};
        acc[t] = tmp;
    }
    #pragma unroll
    for (int s = 0; s < 8; ++s)
        #pragma unroll
        for (int t = 0; t < 2; ++t)
            acc[t] = __builtin_amdgcn_mfma_f32_16x16x32_bf16(af[s], bf[t][s], acc[t], 0, 0, 0);
}

__global__ __launch_bounds__(512, 1) void mlp_kernel(
    const float* __restrict__ x,
    const short8* __restrict__ pw_in, const float* __restrict__ b_in,
    const short8* __restrict__ pwb0,  const float* __restrict__ bb0,
    const short8* __restrict__ pwb1,  const float* __restrict__ bb1,
    const short8* __restrict__ pwb2,  const float* __restrict__ b_out,
    float* __restrict__ w2buf, float* __restrict__ cbuf)
{
    __shared__ short act[2][16 * 256];   // 2 x 8 KB bf16, swizzled
    char* bufA = (char*)&act[0][0];
    char* bufB = (char*)&act[1][0];
    const int lane = threadIdx.x & 63;
    const int w    = threadIdx.x >> 6;      // 0..7
    const int li   = lane & 15, g = lane >> 4;
    const int b0i  = blockIdx.x * 16;

    // ---- issue ALL early loads up front ----
    short8 bin[2];
    #pragma unroll
    for (int t = 0; t < 2; ++t) bin[t] = pw_in[(2 * w + t) * 64 + lane];

    short8 bA[2][8], bB[2][8];
    #pragma unroll
    for (int t = 0; t < 2; ++t)
        #pragma unroll
        for (int s = 0; s < 8; ++s)
            bA[t][s] = pwb0[((2 * w + t) * 8 + s) * 64 + lane];   // layer0 frags

    float bias_in[2], bias0[2], bias1[2], bias2[2];
    #pragma unroll
    for (int t = 0; t < 2; ++t) {
        int j16 = (2 * w + t) * 16 + li;
        bias_in[t] = b_in[j16];
        bias0[t]   = bb0[j16];
        bias1[t]   = bb1[j16];
        bias2[t]   = b_out[j16];
    }

    short8 a0 = {0, 0, 0, 0, 0, 0, 0, 0};
    if (g < 2) {
        const float* xr = x + (b0i + li) * XCOLS + D + g * 8;
        #pragma unroll
        for (int e = 0; e < 8; ++e) a0[e] = (short)rne16(xr[e]);
    }

    f32x4 acc[2];

    // ---- input layer: params -> 256 -> bufA ----
    #pragma unroll
    for (int t = 0; t < 2; ++t) {
        f32x4 tmp = {bias_in[t], bias_in[t], bias_in[t], bias_in[t]};
        acc[t] = __builtin_amdgcn_mfma_f32_16x16x32_bf16(a0, bin[t], tmp, 0, 0, 0);
    }
    store_act16(bufA, acc, li, g, w, true);

    // prefetch layer1 frags before the barrier
    #pragma unroll
    for (int t = 0; t < 2; ++t)
        #pragma unroll
        for (int s = 0; s < 8; ++s)
            bB[t][s] = pwb1[((2 * w + t) * 8 + s) * 64 + lane];
    __syncthreads();

    // ---- layer 0: read bufA, MFMA with bA ----
    hidden_compute(bufA, bA, bias0, li, g, acc);
    store_act16(bufB, acc, li, g, w, true);
    // prefetch layer2 frags (bA registers free after the MFMAs above)
    #pragma unroll
    for (int t = 0; t < 2; ++t)
        #pragma unroll
        for (int s = 0; s < 8; ++s)
            bA[t][s] = pwb2[((2 * w + t) * 8 + s) * 64 + lane];
    __syncthreads();

    // ---- layer 1: read bufB, MFMA with bB ----
    hidden_compute(bufB, bB, bias1, li, g, acc);
    store_act16(bufA, acc, li, g, w, true);
    __syncthreads();

    // ---- layer 2 (out): read bufA, MFMA with bA -> coef ----
    hidden_compute(bufA, bA, bias2, li, g, acc);

    // ---- epilogue: j = (2w+t)*16+li; sample b = b0i + g*4 + r ----
    #pragma unroll
    for (int t = 0; t < 2; ++t) {
        int j = (2 * w + t) * 16 + li;
        #pragma unroll
        for (int r = 0; r < 4; ++r) {
            int b = b0i + g * 4 + r;
            float c = acc[t][r];
            if (j < D) {
                float om = fmaf(c, 1.5f, 0.5f);
                w2buf[b * D + j] = om * om * INV_2PI_F;
            } else {
                cbuf[b * D + (j - D)] = c;
            }
        }
    }
}

// ---------------- ODE: revolution-domain RK4, 2 samples per wave -------------

__device__ __forceinline__ float rot_from_lower(float v) {  // lane n <- lane (n-1)&63
    return __int_as_float(__builtin_amdgcn_mov_dpp(__float_as_int(v), 0x13C, 0xF, 0xF, false)); // wave_ror:1
}
__device__ __forceinline__ float rot_from_upper(float v) {  // lane n <- lane (n+1)&63
    return __int_as_float(__builtin_amdgcn_mov_dpp(__float_as_int(v), 0x134, 0xF, 0xF, false)); // wave_rol:1
}

__global__ __launch_bounds__(256) void ode_kernel(
    const float* __restrict__ x,
    const float* __restrict__ w2buf,
    const float* __restrict__ cbuf,
    float* __restrict__ out,
    int nstep, float dt)
{
    const int lane = threadIdx.x & 63;
    const int wid  = threadIdx.x >> 6;
    const int bA   = blockIdx.x * 8 + wid * 2;   // two consecutive samples

    float th0[2], th1[2], v0[2], v1[2];
    float nw0[2], nw1[2], c0[2], c1[2], cl[2];

    #pragma unroll
    for (int s = 0; s < 2; ++s) {
        int b  = bA + s;
        int i0 = b * D + 2 * lane;
        float2 xi  = *reinterpret_cast<const float2*>(&x[b * XCOLS + 2 * lane]);
        th0[s] = xi.x - 0.5f;            // phi0 = x - 1/2 (revolutions)
        th1[s] = xi.y - 0.5f;
        v0[s] = 0.f; v1[s] = 0.f;
        float2 w2p = *reinterpret_cast<const float2*>(&w2buf[i0]);
        float2 cp  = *reinterpret_cast<const float2*>(&cbuf[i0]);
        nw0[s] = -w2p.x; nw1[s] = -w2p.y;
        c0[s] = cp.x;    c1[s] = cp.y;
        cl[s] = cbuf[(i0 + NTOT - 1) & (NTOT - 1)];   // flat-roll left coupling
    }

    auto deriv = [&](const float t0[2], const float t1[2], float a0[2], float a1[2]) {
        #pragma unroll
        for (int s = 0; s < 2; ++s) {
            float L0 = rot_from_lower(t1[s]);   // phi of osc 2l-1 (wraps 0 -> 127)
            float R1 = rot_from_upper(t0[s]);   // phi of osc 2l+2 (wraps 63 -> 0)
            float s0 = __builtin_amdgcn_sinf(t0[s]);   // sin(2pi*phi), raw v_sin_f32
            float s1 = __builtin_amdgcn_sinf(t1[s]);
            float dd  = t1[s] - t0[s];
            float cpl = c0[s] * dd;
            a0[s] = fmaf(s0, nw0[s], fmaf(cl[s], L0 - t0[s],  cpl));
            a1[s] = fmaf(s1, nw1[s], fmaf(c1[s], R1 - t1[s], -cpl));
        }
    };

    const float hdt   = 0.5f * dt;
    const float sixth = dt * (1.0f / 6.0f);

    for (int it = 0; it < nstep; ++it) {
        float a1_0[2], a1_1[2];
        deriv(th0, th1, a1_0, a1_1);

        float t2_0[2], t2_1[2], k2_0[2], k2_1[2];
        #pragma unroll
        for (int s = 0; s < 2; ++s) {
            t2_0[s] = fmaf(hdt, v0[s], th0[s]);   t2_1[s] = fmaf(hdt, v1[s], th1[s]);
            k2_0[s] = fmaf(hdt, a1_0[s], v0[s]);  k2_1[s] = fmaf(hdt, a1_1[s], v1[s]);
        }
        float a2_0[2], a2_1[2];
        deriv(t2_0, t2_1, a2_0, a2_1);

        float t3_0[2], t3_1[2], k3_0[2], k3_1[2];
        #pragma unroll
        for (int s = 0; s < 2; ++s) {
            t3_0[s] = fmaf(hdt, k2_0[s], th0[s]); t3_1[s] = fmaf(hdt, k2_1[s], th1[s]);
            k3_0[s] = fmaf(hdt, a2_0[s], v0[s]);  k3_1[s] = fmaf(hdt, a2_1[s], v1[s]);
        }
        float a3_0[2], a3_1[2];
        deriv(t3_0, t3_1, a3_0, a3_1);

        float t4_0[2], t4_1[2], k4_0[2], k4_1[2];
        #pragma unroll
        for (int s = 0; s < 2; ++s) {
            t4_0[s] = fmaf(dt, k3_0[s], th0[s]);  t4_1[s] = fmaf(dt, k3_1[s], th1[s]);
            k4_0[s] = fmaf(dt, a3_0[s], v0[s]);   k4_1[s] = fmaf(dt, a3_1[s], v1[s]);
        }
        float a4_0[2], a4_1[2];
        deriv(t4_0, t4_1, a4_0, a4_1);

        #pragma unroll
        for (int s = 0; s < 2; ++s) {
            th0[s] += sixth * (v0[s] + 2.f * (k2_0[s] + k3_0[s]) + k4_0[s]);
            th1[s] += sixth * (v1[s] + 2.f * (k2_1[s] + k3_1[s]) + k4_1[s]);
            v0[s]  += sixth * (a1_0[s] + 2.f * (a2_0[s] + a3_0[s]) + a4_0[s]);
            v1[s]  += sixth * (a1_1[s] + 2.f * (a2_1[s] + a3_1[s]) + a4_1[s]);
        }
    }

    #pragma unroll
    for (int s = 0; s < 2; ++s) {
        int i0 = (bA + s) * D + 2 * lane;
        float2 o = make_float2(th0[s] * OUT_SCALE, th1[s] * OUT_SCALE);
        *reinterpret_cast<float2*>(&out[i0]) = o;
    }
}

extern "C" void kernel_launch(void* const* d_in, const int* in_sizes, int n_in,
                              void* d_out, int out_size, void* d_ws, size_t ws_size,
                              hipStream_t stream) {
    const float* x     = (const float*)d_in[0];
    const float* w_in  = (const float*)d_in[1];
    const float* b_in  = (const float*)d_in[2];
    const float* w0    = (const float*)d_in[3];
    const float* b0    = (const float*)d_in[4];
    const float* w1    = (const float*)d_in[5];
    const float* b1    = (const float*)d_in[6];
    const float* w_out = (const float*)d_in[7];
    const float* b_out = (const float*)d_in[8];

    float* w2buf = (float*)d_ws;                  // omega0^2/(2pi), NTOT floats
    float* cbuf  = w2buf + NTOT;                  // coupling, NTOT floats
    short8* pw_in = (short8*)(cbuf + NTOT);       // 1024 slots x 16 B
    short8* pwb0  = pw_in + 1024;                 // 8192 slots
    short8* pwb1  = pwb0 + 8192;
    short8* pwb2  = pwb1 + 8192;
    float* out   = (float*)d_out;

    pack_kernel<<<100, 256, 0, stream>>>(w_in, w0, w1, w_out,
                                         pw_in, pwb0, pwb1, pwb2);

    mlp_kernel<<<BATCH / 16, 512, 0, stream>>>(
        x, pw_in, b_in, pwb0, b0, pwb1, b1, pwb2, b_out, w2buf, cbuf);

    const int nstep = 8;
    const float dtf = (float)((59.0 / 30.0) / nstep);
    ode_kernel<<<BATCH / 8, 256, 0, stream>>>(x, w2buf, cbuf, out, nstep, dtf);
}